// Round 2
// baseline (1841.462 us; speedup 1.0000x reference)
//
#include <hip/hip_runtime.h>

#define TSTEPS 30
#define KP2 136   // 128 h + 8 pad halfs (272B row stride); gate frags read only k<128

#define LOG2E     1.44269504f
#define TWO_LOG2E 2.88539008f

// R9: XOR element-index bit4 with row bit3 (write-conflict spread). Kept.
#define SWZ(row, e) ((e) ^ ((((row) >> 3) & 1) << 4))

typedef _Float16 half8 __attribute__((ext_vector_type(8)));
typedef _Float16 half4 __attribute__((ext_vector_type(4)));
typedef float f32x4 __attribute__((ext_vector_type(4)));

#if __has_builtin(__builtin_amdgcn_mfma_f32_16x16x16f16)
#define XK16 1
#else
#define XK16 0
#endif

__device__ __forceinline__ float fexp2(float x) { return __builtin_amdgcn_exp2f(x); }
__device__ __forceinline__ float frcp(float x)  { return __builtin_amdgcn_rcpf(x); }
__device__ __forceinline__ float fsig_pre(float x)  { return frcp(1.0f + fexp2(-x)); }
__device__ __forceinline__ float ftanh_pre(float x) { return 1.0f - 2.0f * frcp(1.0f + fexp2(x)); }

// R10: occupancy lever. Measured OccupancyPercent ~23.8% = exactly 1 block/CU:
// arch VGPR 104 + ~32 AGPR acc > 128/lane caps us at 2 waves/SIMD. Fix:
//  - __launch_bounds__(512, 4): force total regs <= 128 -> 2 blocks/CU, so one
//    block's barrier drain is filled by the other block's issue.
//  - Ef fragments (16 VGPRs, used by only 4 waves) move to a 10 KB LDS table
//    (rows padded to 80 B: dword start = 20*L mod 32 covers all 32 banks at
//    the 8-dwords/bank minimum). Loaded one fragment at a time per use, so
//    transient pressure is +4 regs, not +16.
// Everything else identical to the 584 us baseline (dual-acc pipeline, SWZ, XK16).
__global__ __launch_bounds__(512, 4)
void lstm30_kernel(const float* __restrict__ last_obs_rel,
                   const float* __restrict__ h0,
                   const float* __restrict__ c0,
                   const float* __restrict__ W_sp,
                   const float* __restrict__ b_sp,
                   const float* __restrict__ W_ih,
                   const float* __restrict__ b_ih,
                   const float* __restrict__ W_hh,
                   const float* __restrict__ b_hh,
                   const float* __restrict__ W_out,
                   const float* __restrict__ b_out,
                   float* __restrict__ out)
{
    __shared__ _Float16 hA[32][KP2];
    __shared__ _Float16 lA[32][KP2];
#if XK16
    __shared__ _Float16 xS[2][16][20];
#else
    __shared__ _Float16 xS[2][16][32];
#endif
    // Ef table: [0] = M-path (waves 0/1), [1] = Wout-path (waves 2/3).
    // Values depend only on (lane, variant); w0/w2 fill, w1/w3 reuse.
    __shared__ __align__(16) _Float16 efS[2][64][40];

    const int tid  = threadIdx.x;
    const int w    = tid >> 6;
    const int L    = tid & 63;
    const int quad = L >> 4;
    const int col  = L & 15;
    const int base = blockIdx.x << 5;

    // ---- gate B fragments: W'[k][G], G = nt*128 + 16w + col, pre-scaled ----
#if XK16
    half8 Wf[4][4];
    half4 Wf4[4];
#else
    half8 Wf[4][5];
#endif
    float bias[4];
    #pragma unroll
    for (int nt = 0; nt < 4; ++nt) {
        const int G = nt * 128 + w * 16 + col;
        const float gsc = (nt == 2) ? TWO_LOG2E : LOG2E;
        bias[nt] = (b_ih[G] + b_hh[G]) * gsc;
        #pragma unroll
        for (int kc = 0; kc < 4; ++kc) {
            const int k0 = kc * 32 + quad * 8;
            const float4 a = *(const float4*)&W_hh[G * 128 + k0];
            const float4 b = *(const float4*)&W_hh[G * 128 + k0 + 4];
            half8 hh;
            hh[0] = (_Float16)(a.x * gsc); hh[1] = (_Float16)(a.y * gsc);
            hh[2] = (_Float16)(a.z * gsc); hh[3] = (_Float16)(a.w * gsc);
            hh[4] = (_Float16)(b.x * gsc); hh[5] = (_Float16)(b.y * gsc);
            hh[6] = (_Float16)(b.z * gsc); hh[7] = (_Float16)(b.w * gsc);
            Wf[nt][kc] = hh;
        }
#if XK16
        {
            const float4 a = *(const float4*)&W_ih[G * 16 + quad * 4];
            half4 h4;
            h4[0] = (_Float16)(a.x * gsc); h4[1] = (_Float16)(a.y * gsc);
            h4[2] = (_Float16)(a.z * gsc); h4[3] = (_Float16)(a.w * gsc);
            Wf4[nt] = h4;
        }
#else
        {
            const int k0 = 128 + quad * 8;
            float v[8];
            if (k0 < 144) {
                const float4 a = *(const float4*)&W_ih[G * 16 + (k0 - 128)];
                const float4 b = *(const float4*)&W_ih[G * 16 + (k0 - 128) + 4];
                v[0]=a.x; v[1]=a.y; v[2]=a.z; v[3]=a.w;
                v[4]=b.x; v[5]=b.y; v[6]=b.z; v[7]=b.w;
            } else {
                #pragma unroll
                for (int jj = 0; jj < 8; ++jj) v[jj] = 0.0f;
            }
            half8 hh;
            #pragma unroll
            for (int jj = 0; jj < 8; ++jj) hh[jj] = (_Float16)(v[jj] * gsc);
            Wf[nt][4] = hh;
        }
#endif
    }

    const float ws0 = W_sp[col * 2 + 0];
    const float ws1 = W_sp[col * 2 + 1];
    const float bs  = b_sp[col];
    const float bo0 = b_out[0], bo1 = b_out[1];

    // ---- Ef fragments -> LDS (R10); einit stays a register ----
    float einit;
    {
        const bool isM = (w < 2);
        einit = isM ? (ws0 * bo0 + ws1 * bo1 + bs) * TWO_LOG2E
                    : ((col == 0) ? bo0 : (col == 1) ? bo1 : 0.0f);
        if (w == 0 || w == 2) {
            #pragma unroll
            for (int kc = 0; kc < 4; ++kc) {
                const int k0 = kc * 32 + quad * 8;
                const float4 a0 = *(const float4*)&W_out[k0];
                const float4 a1 = *(const float4*)&W_out[k0 + 4];
                const float4 b0 = *(const float4*)&W_out[128 + k0];
                const float4 b1 = *(const float4*)&W_out[128 + k0 + 4];
                float r0[8] = {a0.x,a0.y,a0.z,a0.w,a1.x,a1.y,a1.z,a1.w};
                float r1[8] = {b0.x,b0.y,b0.z,b0.w,b1.x,b1.y,b1.z,b1.w};
                half8 he;
                #pragma unroll
                for (int jj = 0; jj < 8; ++jj)
                    he[jj] = isM ? (_Float16)((ws0 * r0[jj] + ws1 * r1[jj]) * TWO_LOG2E)
                                 : (_Float16)((col == 0) ? r0[jj] : (col == 1) ? r1[jj] : 0.0f);
                *(half8*)&efS[w >> 1][L][kc * 8] = he;
            }
        }
    }

    float c[2][4];
    #pragma unroll
    for (int tt = 0; tt < 2; ++tt)
        #pragma unroll
        for (int r = 0; r < 4; ++r)
            c[tt][r] = c0[(base + tt * 16 + quad * 4 + r) * 128 + w * 16 + col];

    // ---- prologue ----
    for (int idx = tid; idx < 32 * 128; idx += 512) {
        const int r = idx >> 7, k = idx & 127;
        const float v = h0[base * 128 + idx];
        const _Float16 hi = (_Float16)v;
        hA[r][SWZ(r, k)] = hi;
        lA[r][SWZ(r, k)] = (_Float16)(v - (float)hi);
    }
    {
        const int rr = tid >> 4;
        const float p0 = last_obs_rel[(base + rr) * 2 + 0];
        const float p1 = last_obs_rel[(base + rr) * 2 + 1];
        xS[rr >> 4][rr & 15][tid & 15] = (_Float16)ftanh_pre(TWO_LOG2E * (ws0 * p0 + ws1 * p1 + bs));
    }
#if !XK16
    for (int flat = tid; flat < 2 * 16 * 16; flat += 512) {
        const int T = flat >> 8, row = (flat >> 4) & 15;
        xS[T][row][16 + (flat & 15)] = (_Float16)0.0f;
    }
#endif
    __syncthreads();

    const int j = w * 16 + col;
    f32x4 accA[4], accB[4];

    for (int k = 0; k < TSTEPS; ++k) {
        // ================= EVEN: gates(A,k) hi-only ; x+cell(B,k-1) =================
        {
            half8 a[4];
            #pragma unroll
            for (int kc = 0; kc < 4; ++kc)
                a[kc] = *(const half8*)&hA[col][SWZ(col, kc * 32 + quad * 8)];

            if (k > 0) {   // finish gates(B,k-1): x part
#if XK16
                const half4 xb = *(const half4*)&xS[1][col][quad * 4];
                #pragma unroll
                for (int nt = 0; nt < 4; ++nt)
                    accB[nt] = __builtin_amdgcn_mfma_f32_16x16x16f16(xb, Wf4[nt], accB[nt], 0, 0, 0);
#else
                const half8 xb = *(const half8*)&xS[1][col][quad * 8];
                #pragma unroll
                for (int nt = 0; nt < 4; ++nt)
                    accB[nt] = __builtin_amdgcn_mfma_f32_16x16x32_f16(xb, Wf[nt][4], accB[nt], 0, 0, 0);
#endif
            }

            #pragma unroll
            for (int nt = 0; nt < 4; ++nt) {
                f32x4 bv = {bias[nt], bias[nt], bias[nt], bias[nt]};
                accA[nt] = bv;
            }
            f32x4 eacc = {einit, einit, einit, einit};

            #pragma unroll
            for (int kc = 0; kc < 4; ++kc)
                #pragma unroll
                for (int nt = 0; nt < 4; ++nt)
                    accA[nt] = __builtin_amdgcn_mfma_f32_16x16x32_f16(a[kc], Wf[nt][kc], accA[nt], 0, 0, 0);

            if (k > 0) {   // cell(B,k-1) rows 0-1 — VALU overlaps MFMA drain
                #pragma unroll
                for (int r = 0; r < 2; ++r) {
                    const int row = 16 + quad * 4 + r;
                    const float gi = fsig_pre(accB[0][r]);
                    const float gf = fsig_pre(accB[1][r]);
                    const float gg = ftanh_pre(accB[2][r]);
                    const float go = fsig_pre(accB[3][r]);
                    c[1][r] = gf * c[1][r] + gi * gg;
                    const float h = go * ftanh_pre(TWO_LOG2E * c[1][r]);
                    const _Float16 hi = (_Float16)h;
                    hA[row][SWZ(row, j)] = hi;
                    lA[row][SWZ(row, j)] = (_Float16)(h - (float)hi);
                }
            }

            if (k > 0 && w == 0) {        // x-path: hi only
                #pragma unroll
                for (int kc = 0; kc < 4; ++kc) {
                    const half8 ef = *(const half8*)&efS[0][L][kc * 8];
                    eacc = __builtin_amdgcn_mfma_f32_16x16x32_f16(a[kc], ef, eacc, 0, 0, 0);
                }
            }
            if (k > 0 && w == 2) {        // rel-path: hi + lo (output precision)
                #pragma unroll
                for (int kc = 0; kc < 4; ++kc) {
                    const half8 ef = *(const half8*)&efS[1][L][kc * 8];
                    eacc = __builtin_amdgcn_mfma_f32_16x16x32_f16(a[kc], ef, eacc, 0, 0, 0);
                }
                #pragma unroll
                for (int kc = 0; kc < 4; ++kc) {
                    const half8 aL = *(const half8*)&lA[col][SWZ(col, kc * 32 + quad * 8)];
                    const half8 ef = *(const half8*)&efS[1][L][kc * 8];
                    eacc = __builtin_amdgcn_mfma_f32_16x16x32_f16(aL, ef, eacc, 0, 0, 0);
                }
            }

            if (k > 0) {   // cell(B,k-1) rows 2-3
                #pragma unroll
                for (int r = 2; r < 4; ++r) {
                    const int row = 16 + quad * 4 + r;
                    const float gi = fsig_pre(accB[0][r]);
                    const float gf = fsig_pre(accB[1][r]);
                    const float gg = ftanh_pre(accB[2][r]);
                    const float go = fsig_pre(accB[3][r]);
                    c[1][r] = gf * c[1][r] + gi * gg;
                    const float h = go * ftanh_pre(TWO_LOG2E * c[1][r]);
                    const _Float16 hi = (_Float16)h;
                    hA[row][SWZ(row, j)] = hi;
                    lA[row][SWZ(row, j)] = (_Float16)(h - (float)hi);
                }
            }

            if (k > 0 && w == 0) {   // x_k(A); k=0 keeps obs-x0 (R4 lesson)
                #pragma unroll
                for (int r = 0; r < 4; ++r)
                    xS[0][quad * 4 + r][col] = (_Float16)ftanh_pre(eacc[r]);
            }
            if (k > 0 && w == 2 && col < 2) {   // rel_{k-1}(A)
                #pragma unroll
                for (int r = 0; r < 4; ++r)
                    out[(base + quad * 4 + r) * (TSTEPS * 2) + (k - 1) * 2 + col] = eacc[r];
            }
            __syncthreads();
        }
        // ================= ODD: gates(B,k) hi-only ; x+cell(A,k) =================
        {
            half8 a[4];
            #pragma unroll
            for (int kc = 0; kc < 4; ++kc)
                a[kc] = *(const half8*)&hA[16 + col][SWZ(16 + col, kc * 32 + quad * 8)];

            {   // finish gates(A,k): x part (xS[0] = obs-x0 at k=0, else wave0's write)
#if XK16
                const half4 xa = *(const half4*)&xS[0][col][quad * 4];
                #pragma unroll
                for (int nt = 0; nt < 4; ++nt)
                    accA[nt] = __builtin_amdgcn_mfma_f32_16x16x16f16(xa, Wf4[nt], accA[nt], 0, 0, 0);
#else
                const half8 xa = *(const half8*)&xS[0][col][quad * 8];
                #pragma unroll
                for (int nt = 0; nt < 4; ++nt)
                    accA[nt] = __builtin_amdgcn_mfma_f32_16x16x32_f16(xa, Wf[nt][4], accA[nt], 0, 0, 0);
#endif
            }

            #pragma unroll
            for (int nt = 0; nt < 4; ++nt) {
                f32x4 bv = {bias[nt], bias[nt], bias[nt], bias[nt]};
                accB[nt] = bv;
            }
            f32x4 eacc = {einit, einit, einit, einit};

            #pragma unroll
            for (int kc = 0; kc < 4; ++kc)
                #pragma unroll
                for (int nt = 0; nt < 4; ++nt)
                    accB[nt] = __builtin_amdgcn_mfma_f32_16x16x32_f16(a[kc], Wf[nt][kc], accB[nt], 0, 0, 0);

            {   // cell(A,k) rows 0-1
                #pragma unroll
                for (int r = 0; r < 2; ++r) {
                    const int row = quad * 4 + r;
                    const float gi = fsig_pre(accA[0][r]);
                    const float gf = fsig_pre(accA[1][r]);
                    const float gg = ftanh_pre(accA[2][r]);
                    const float go = fsig_pre(accA[3][r]);
                    c[0][r] = gf * c[0][r] + gi * gg;
                    const float h = go * ftanh_pre(TWO_LOG2E * c[0][r]);
                    const _Float16 hi = (_Float16)h;
                    hA[row][SWZ(row, j)] = hi;
                    lA[row][SWZ(row, j)] = (_Float16)(h - (float)hi);
                }
            }

            if (w == 1) {        // x-path: hi only
                #pragma unroll
                for (int kc = 0; kc < 4; ++kc) {
                    const half8 ef = *(const half8*)&efS[0][L][kc * 8];
                    eacc = __builtin_amdgcn_mfma_f32_16x16x32_f16(a[kc], ef, eacc, 0, 0, 0);
                }
            }
            if (w == 3) {        // rel-path: hi + lo
                #pragma unroll
                for (int kc = 0; kc < 4; ++kc) {
                    const half8 ef = *(const half8*)&efS[1][L][kc * 8];
                    eacc = __builtin_amdgcn_mfma_f32_16x16x32_f16(a[kc], ef, eacc, 0, 0, 0);
                }
                #pragma unroll
                for (int kc = 0; kc < 4; ++kc) {
                    const half8 aL = *(const half8*)&lA[16 + col][SWZ(16 + col, kc * 32 + quad * 8)];
                    const half8 ef = *(const half8*)&efS[1][L][kc * 8];
                    eacc = __builtin_amdgcn_mfma_f32_16x16x32_f16(aL, ef, eacc, 0, 0, 0);
                }
            }

            {   // cell(A,k) rows 2-3
                #pragma unroll
                for (int r = 2; r < 4; ++r) {
                    const int row = quad * 4 + r;
                    const float gi = fsig_pre(accA[0][r]);
                    const float gf = fsig_pre(accA[1][r]);
                    const float gg = ftanh_pre(accA[2][r]);
                    const float go = fsig_pre(accA[3][r]);
                    c[0][r] = gf * c[0][r] + gi * gg;
                    const float h = go * ftanh_pre(TWO_LOG2E * c[0][r]);
                    const _Float16 hi = (_Float16)h;
                    hA[row][SWZ(row, j)] = hi;
                    lA[row][SWZ(row, j)] = (_Float16)(h - (float)hi);
                }
            }

            if (k > 0 && w == 1) {   // x_k(B); k=0 keeps obs-x0
                #pragma unroll
                for (int r = 0; r < 4; ++r)
                    xS[1][quad * 4 + r][col] = (_Float16)ftanh_pre(eacc[r]);
            }
            if (k > 0 && w == 3 && col < 2) {   // rel_{k-1}(B)
                #pragma unroll
                for (int r = 0; r < 4; ++r)
                    out[(base + 16 + quad * 4 + r) * (TSTEPS * 2) + (k - 1) * 2 + col] = eacc[r];
            }
            __syncthreads();
        }
    }

    // ================= epilogue: finish B step 29; rel_29 both tiles (hi+lo) =================
    {
        {
#if XK16
            const half4 xb = *(const half4*)&xS[1][col][quad * 4];
            #pragma unroll
            for (int nt = 0; nt < 4; ++nt)
                accB[nt] = __builtin_amdgcn_mfma_f32_16x16x16f16(xb, Wf4[nt], accB[nt], 0, 0, 0);
#else
            const half8 xb = *(const half8*)&xS[1][col][quad * 8];
            #pragma unroll
            for (int nt = 0; nt < 4; ++nt)
                accB[nt] = __builtin_amdgcn_mfma_f32_16x16x32_f16(xb, Wf[nt][4], accB[nt], 0, 0, 0);
#endif
        }
        if (w == 2) {   // rel_29(A) from h_30(A)
            f32x4 eacc = {einit, einit, einit, einit};
            #pragma unroll
            for (int kc = 0; kc < 4; ++kc) {
                const half8 aH = *(const half8*)&hA[col][SWZ(col, kc * 32 + quad * 8)];
                const half8 ef = *(const half8*)&efS[1][L][kc * 8];
                eacc = __builtin_amdgcn_mfma_f32_16x16x32_f16(aH, ef, eacc, 0, 0, 0);
            }
            #pragma unroll
            for (int kc = 0; kc < 4; ++kc) {
                const half8 aL = *(const half8*)&lA[col][SWZ(col, kc * 32 + quad * 8)];
                const half8 ef = *(const half8*)&efS[1][L][kc * 8];
                eacc = __builtin_amdgcn_mfma_f32_16x16x32_f16(aL, ef, eacc, 0, 0, 0);
            }
            if (col < 2) {
                #pragma unroll
                for (int r = 0; r < 4; ++r)
                    out[(base + quad * 4 + r) * (TSTEPS * 2) + (TSTEPS - 1) * 2 + col] = eacc[r];
            }
        }
        #pragma unroll
        for (int r = 0; r < 4; ++r) {   // cell(B,29) -> h_30(B)
            const int row = 16 + quad * 4 + r;
            const float gi = fsig_pre(accB[0][r]);
            const float gf = fsig_pre(accB[1][r]);
            const float gg = ftanh_pre(accB[2][r]);
            const float go = fsig_pre(accB[3][r]);
            c[1][r] = gf * c[1][r] + gi * gg;
            const float h = go * ftanh_pre(TWO_LOG2E * c[1][r]);
            const _Float16 hi = (_Float16)h;
            hA[row][SWZ(row, j)] = hi;
            lA[row][SWZ(row, j)] = (_Float16)(h - (float)hi);
        }
        __syncthreads();
        if (w == 3) {   // rel_29(B) from h_30(B)
            f32x4 eacc = {einit, einit, einit, einit};
            #pragma unroll
            for (int kc = 0; kc < 4; ++kc) {
                const half8 aH = *(const half8*)&hA[16 + col][SWZ(16 + col, kc * 32 + quad * 8)];
                const half8 ef = *(const half8*)&efS[1][L][kc * 8];
                eacc = __builtin_amdgcn_mfma_f32_16x16x32_f16(aH, ef, eacc, 0, 0, 0);
            }
            #pragma unroll
            for (int kc = 0; kc < 4; ++kc) {
                const half8 aL = *(const half8*)&lA[16 + col][SWZ(16 + col, kc * 32 + quad * 8)];
                const half8 ef = *(const half8*)&efS[1][L][kc * 8];
                eacc = __builtin_amdgcn_mfma_f32_16x16x32_f16(aL, ef, eacc, 0, 0, 0);
            }
            if (col < 2) {
                #pragma unroll
                for (int r = 0; r < 4; ++r)
                    out[(base + 16 + quad * 4 + r) * (TSTEPS * 2) + (TSTEPS - 1) * 2 + col] = eacc[r];
            }
        }
    }
}

extern "C" void kernel_launch(void* const* d_in, const int* in_sizes, int n_in,
                              void* d_out, int out_size, void* d_ws, size_t ws_size,
                              hipStream_t stream) {
    const float* last_obs_rel = (const float*)d_in[1];
    const float* h0    = (const float*)d_in[2];
    const float* c0    = (const float*)d_in[3];
    const float* W_sp  = (const float*)d_in[4];
    const float* b_sp  = (const float*)d_in[5];
    const float* W_ih  = (const float*)d_in[6];
    const float* b_ih  = (const float*)d_in[7];
    const float* W_hh  = (const float*)d_in[8];
    const float* b_hh  = (const float*)d_in[9];
    const float* W_out = (const float*)d_in[10];
    const float* b_out = (const float*)d_in[11];
    float* out = (float*)d_out;

    const int batch = in_sizes[2] / 128;   // 65536
    lstm30_kernel<<<dim3(batch / 32), dim3(512), 0, stream>>>(
        last_obs_rel, h0, c0, W_sp, b_sp, W_ih, b_ih, W_hh, b_hh, W_out, b_out, out);
}

// Round 3
// 592.339 us; speedup vs baseline: 3.1088x; 3.1088x over previous
//
#include <hip/hip_runtime.h>

#define TSTEPS 30
#define KP2 136   // 128 h + 8 pad halfs (272B row stride); gate frags read only k<128

#define LOG2E     1.44269504f
#define TWO_LOG2E 2.88539008f

// R9: XOR element-index bit4 with row bit3 (write-conflict spread). Kept.
#define SWZ(row, e) ((e) ^ ((((row) >> 3) & 1) << 4))

typedef _Float16 half8 __attribute__((ext_vector_type(8)));
typedef _Float16 half4 __attribute__((ext_vector_type(4)));
typedef float f32x4 __attribute__((ext_vector_type(4)));

#if __has_builtin(__builtin_amdgcn_mfma_f32_16x16x16f16)
#define XK16 1
#else
#define XK16 0
#endif

__device__ __forceinline__ float fexp2(float x) { return __builtin_amdgcn_exp2f(x); }
__device__ __forceinline__ float frcp(float x)  { return __builtin_amdgcn_rcpf(x); }
__device__ __forceinline__ float fsig_pre(float x)  { return frcp(1.0f + fexp2(-x)); }
__device__ __forceinline__ float ftanh_pre(float x) { return 1.0f - 2.0f * frcp(1.0f + fexp2(x)); }

// R11: 64 rows/block (tiles T0..T3), 8 waves, ILP doubled at fixed occupancy.
// R2 lesson: register cap below true pressure (launch_bounds 512,4) spilled W
// fragments -> 5.8 GB scratch traffic, 3x slower. Occupancy is structurally
// 1 block/CU (2 waves/SIMD); per-SIMD pipes were ~80% idle (MfmaUtil 26% /
// VALUBusy 51% are per-CU sums over 4 SIMDs). So: amortize the fixed per-phase
// serial chain (barrier + ds_read + MFMA-chain + exp2/rcp chain) over 2x
// independent work per wave. Even phase: gates(T0,T2,k) + cell(T1,T3,k-1);
// odd phase: mirror. e-jobs one per wave: w0/w1 x(T0/T2), w2/w3 rel(T0/T2)
// even; w4/w5 x(T1/T3), w6/w7 rel(T1/T3) odd.
#define CELL_ROW(ACC, CC, ROW, R) do {                                  \
    const float gi_ = fsig_pre(ACC[0][R]);                              \
    const float gf_ = fsig_pre(ACC[1][R]);                              \
    const float gg_ = ftanh_pre(ACC[2][R]);                             \
    const float go_ = fsig_pre(ACC[3][R]);                              \
    CC = gf_ * CC + gi_ * gg_;                                          \
    const float hv_ = go_ * ftanh_pre(TWO_LOG2E * CC);                  \
    const _Float16 hh_ = (_Float16)hv_;                                 \
    const int row_ = (ROW);                                             \
    hS[row_][SWZ(row_, j)] = hh_;                                       \
    lS[row_][SWZ(row_, j)] = (_Float16)(hv_ - (float)hh_);              \
} while (0)

__global__ __launch_bounds__(512, 2)
void lstm30_kernel(const float* __restrict__ last_obs_rel,
                   const float* __restrict__ h0,
                   const float* __restrict__ c0,
                   const float* __restrict__ W_sp,
                   const float* __restrict__ b_sp,
                   const float* __restrict__ W_ih,
                   const float* __restrict__ b_ih,
                   const float* __restrict__ W_hh,
                   const float* __restrict__ b_hh,
                   const float* __restrict__ W_out,
                   const float* __restrict__ b_out,
                   float* __restrict__ out)
{
    __shared__ _Float16 hS[64][KP2];
    __shared__ _Float16 lS[64][KP2];
#if XK16
    __shared__ _Float16 xS[4][16][20];
#else
    __shared__ _Float16 xS[4][16][32];
#endif

    const int tid  = threadIdx.x;
    const int w    = tid >> 6;
    const int L    = tid & 63;
    const int quad = L >> 4;
    const int col  = L & 15;
    const int base = blockIdx.x << 6;   // 64 rows/block

    // ---- gate B fragments: W'[k][G], G = nt*128 + 16w + col, pre-scaled ----
#if XK16
    half8 Wf[4][4];
    half4 Wf4[4];
#else
    half8 Wf[4][5];
#endif
    float bias[4];
    #pragma unroll
    for (int nt = 0; nt < 4; ++nt) {
        const int G = nt * 128 + w * 16 + col;
        const float gsc = (nt == 2) ? TWO_LOG2E : LOG2E;
        bias[nt] = (b_ih[G] + b_hh[G]) * gsc;
        #pragma unroll
        for (int kc = 0; kc < 4; ++kc) {
            const int k0 = kc * 32 + quad * 8;
            const float4 a = *(const float4*)&W_hh[G * 128 + k0];
            const float4 b = *(const float4*)&W_hh[G * 128 + k0 + 4];
            half8 hh;
            hh[0] = (_Float16)(a.x * gsc); hh[1] = (_Float16)(a.y * gsc);
            hh[2] = (_Float16)(a.z * gsc); hh[3] = (_Float16)(a.w * gsc);
            hh[4] = (_Float16)(b.x * gsc); hh[5] = (_Float16)(b.y * gsc);
            hh[6] = (_Float16)(b.z * gsc); hh[7] = (_Float16)(b.w * gsc);
            Wf[nt][kc] = hh;
        }
#if XK16
        {
            const float4 a = *(const float4*)&W_ih[G * 16 + quad * 4];
            half4 h4;
            h4[0] = (_Float16)(a.x * gsc); h4[1] = (_Float16)(a.y * gsc);
            h4[2] = (_Float16)(a.z * gsc); h4[3] = (_Float16)(a.w * gsc);
            Wf4[nt] = h4;
        }
#else
        {
            const int k0 = 128 + quad * 8;
            float v[8];
            if (k0 < 144) {
                const float4 a = *(const float4*)&W_ih[G * 16 + (k0 - 128)];
                const float4 b = *(const float4*)&W_ih[G * 16 + (k0 - 128) + 4];
                v[0]=a.x; v[1]=a.y; v[2]=a.z; v[3]=a.w;
                v[4]=b.x; v[5]=b.y; v[6]=b.z; v[7]=b.w;
            } else {
                #pragma unroll
                for (int jj = 0; jj < 8; ++jj) v[jj] = 0.0f;
            }
            half8 hh;
            #pragma unroll
            for (int jj = 0; jj < 8; ++jj) hh[jj] = (_Float16)(v[jj] * gsc);
            Wf[nt][4] = hh;
        }
#endif
    }

    const float ws0 = W_sp[col * 2 + 0];
    const float ws1 = W_sp[col * 2 + 1];
    const float bs  = b_sp[col];
    const float bo0 = b_out[0], bo1 = b_out[1];

    // ---- every wave holds ONE Ef variant: M-path (w0,1,4,5) or Wout (w2,3,6,7) ----
    half8 Ef[4];
    float einit;
    {
        const bool isM = ((w & 2) == 0);
        #pragma unroll
        for (int kc = 0; kc < 4; ++kc) {
            const int k0 = kc * 32 + quad * 8;
            const float4 a0 = *(const float4*)&W_out[k0];
            const float4 a1 = *(const float4*)&W_out[k0 + 4];
            const float4 b0 = *(const float4*)&W_out[128 + k0];
            const float4 b1 = *(const float4*)&W_out[128 + k0 + 4];
            float r0[8] = {a0.x,a0.y,a0.z,a0.w,a1.x,a1.y,a1.z,a1.w};
            float r1[8] = {b0.x,b0.y,b0.z,b0.w,b1.x,b1.y,b1.z,b1.w};
            half8 he;
            #pragma unroll
            for (int jj = 0; jj < 8; ++jj)
                he[jj] = isM ? (_Float16)((ws0 * r0[jj] + ws1 * r1[jj]) * TWO_LOG2E)
                             : (_Float16)((col == 0) ? r0[jj] : (col == 1) ? r1[jj] : 0.0f);
            Ef[kc] = he;
        }
        einit = isM ? (ws0 * bo0 + ws1 * bo1 + bs) * TWO_LOG2E
                    : ((col == 0) ? bo0 : (col == 1) ? bo1 : 0.0f);
    }

    float c[4][4];
    #pragma unroll
    for (int t = 0; t < 4; ++t)
        #pragma unroll
        for (int r = 0; r < 4; ++r)
            c[t][r] = c0[(base + t * 16 + quad * 4 + r) * 128 + w * 16 + col];

    // ---- prologue ----
    for (int idx = tid; idx < 64 * 128; idx += 512) {
        const int r = idx >> 7, kk = idx & 127;
        const float v = h0[base * 128 + idx];
        const _Float16 hi = (_Float16)v;
        hS[r][SWZ(r, kk)] = hi;
        lS[r][SWZ(r, kk)] = (_Float16)(v - (float)hi);
    }
    #pragma unroll
    for (int hlf = 0; hlf < 2; ++hlf) {
        const int rr = (tid >> 4) + hlf * 32;
        const float p0 = last_obs_rel[(base + rr) * 2 + 0];
        const float p1 = last_obs_rel[(base + rr) * 2 + 1];
        xS[rr >> 4][rr & 15][tid & 15] = (_Float16)ftanh_pre(TWO_LOG2E * (ws0 * p0 + ws1 * p1 + bs));
    }
#if !XK16
    for (int flat = tid; flat < 4 * 16 * 16; flat += 512) {
        xS[flat >> 8][(flat >> 4) & 15][16 + (flat & 15)] = (_Float16)0.0f;
    }
#endif
    __syncthreads();

    const int j = w * 16 + col;
    f32x4 accT0[4], accT1[4], accT2[4], accT3[4];

    for (int k = 0; k < TSTEPS; ++k) {
        // ============ EVEN: gates(T0,T2;k) h-part ; finish+cell(T1,T3;k-1) ============
        {
            half8 a0[4], a2[4];
            #pragma unroll
            for (int kc = 0; kc < 4; ++kc) {
                a0[kc] = *(const half8*)&hS[col][SWZ(col, kc * 32 + quad * 8)];
                a2[kc] = *(const half8*)&hS[32 + col][SWZ(32 + col, kc * 32 + quad * 8)];
            }

            if (k > 0) {   // finish gates(T1,T3;k-1): x part
#if XK16
                const half4 x1 = *(const half4*)&xS[1][col][quad * 4];
                const half4 x3 = *(const half4*)&xS[3][col][quad * 4];
                #pragma unroll
                for (int nt = 0; nt < 4; ++nt) {
                    accT1[nt] = __builtin_amdgcn_mfma_f32_16x16x16f16(x1, Wf4[nt], accT1[nt], 0, 0, 0);
                    accT3[nt] = __builtin_amdgcn_mfma_f32_16x16x16f16(x3, Wf4[nt], accT3[nt], 0, 0, 0);
                }
#else
                const half8 x1 = *(const half8*)&xS[1][col][quad * 8];
                const half8 x3 = *(const half8*)&xS[3][col][quad * 8];
                #pragma unroll
                for (int nt = 0; nt < 4; ++nt) {
                    accT1[nt] = __builtin_amdgcn_mfma_f32_16x16x32_f16(x1, Wf[nt][4], accT1[nt], 0, 0, 0);
                    accT3[nt] = __builtin_amdgcn_mfma_f32_16x16x32_f16(x3, Wf[nt][4], accT3[nt], 0, 0, 0);
                }
#endif
            }

            #pragma unroll
            for (int nt = 0; nt < 4; ++nt) {
                f32x4 bv = {bias[nt], bias[nt], bias[nt], bias[nt]};
                accT0[nt] = bv;
                accT2[nt] = bv;
            }
            f32x4 eacc = {einit, einit, einit, einit};

            #pragma unroll
            for (int kc = 0; kc < 4; ++kc)
                #pragma unroll
                for (int nt = 0; nt < 4; ++nt) {
                    accT0[nt] = __builtin_amdgcn_mfma_f32_16x16x32_f16(a0[kc], Wf[nt][kc], accT0[nt], 0, 0, 0);
                    accT2[nt] = __builtin_amdgcn_mfma_f32_16x16x32_f16(a2[kc], Wf[nt][kc], accT2[nt], 0, 0, 0);
                }

            if (k > 0) {   // cell(T1,T3;k-1) rows 0-1 — VALU overlaps MFMA drain
                #pragma unroll
                for (int r = 0; r < 2; ++r) {
                    CELL_ROW(accT1, c[1][r], 16 + quad * 4 + r, r);
                    CELL_ROW(accT3, c[3][r], 48 + quad * 4 + r, r);
                }
            }

            if (k > 0 && w == 0) {        // x(T0): hi only
                #pragma unroll
                for (int kc = 0; kc < 4; ++kc)
                    eacc = __builtin_amdgcn_mfma_f32_16x16x32_f16(a0[kc], Ef[kc], eacc, 0, 0, 0);
            }
            if (k > 0 && w == 1) {        // x(T2): hi only
                #pragma unroll
                for (int kc = 0; kc < 4; ++kc)
                    eacc = __builtin_amdgcn_mfma_f32_16x16x32_f16(a2[kc], Ef[kc], eacc, 0, 0, 0);
            }
            if (k > 0 && w == 2) {        // rel(T0): hi + lo
                #pragma unroll
                for (int kc = 0; kc < 4; ++kc)
                    eacc = __builtin_amdgcn_mfma_f32_16x16x32_f16(a0[kc], Ef[kc], eacc, 0, 0, 0);
                #pragma unroll
                for (int kc = 0; kc < 4; ++kc) {
                    const half8 aL = *(const half8*)&lS[col][SWZ(col, kc * 32 + quad * 8)];
                    eacc = __builtin_amdgcn_mfma_f32_16x16x32_f16(aL, Ef[kc], eacc, 0, 0, 0);
                }
            }
            if (k > 0 && w == 3) {        // rel(T2): hi + lo
                #pragma unroll
                for (int kc = 0; kc < 4; ++kc)
                    eacc = __builtin_amdgcn_mfma_f32_16x16x32_f16(a2[kc], Ef[kc], eacc, 0, 0, 0);
                #pragma unroll
                for (int kc = 0; kc < 4; ++kc) {
                    const half8 aL = *(const half8*)&lS[32 + col][SWZ(32 + col, kc * 32 + quad * 8)];
                    eacc = __builtin_amdgcn_mfma_f32_16x16x32_f16(aL, Ef[kc], eacc, 0, 0, 0);
                }
            }

            if (k > 0) {   // cell(T1,T3;k-1) rows 2-3
                #pragma unroll
                for (int r = 2; r < 4; ++r) {
                    CELL_ROW(accT1, c[1][r], 16 + quad * 4 + r, r);
                    CELL_ROW(accT3, c[3][r], 48 + quad * 4 + r, r);
                }
            }

            if (k > 0 && w == 0) {   // x_k(T0); k=0 keeps obs-x0
                #pragma unroll
                for (int r = 0; r < 4; ++r)
                    xS[0][quad * 4 + r][col] = (_Float16)ftanh_pre(eacc[r]);
            }
            if (k > 0 && w == 1) {   // x_k(T2)
                #pragma unroll
                for (int r = 0; r < 4; ++r)
                    xS[2][quad * 4 + r][col] = (_Float16)ftanh_pre(eacc[r]);
            }
            if (k > 0 && w == 2 && col < 2) {   // rel_{k-1}(T0)
                #pragma unroll
                for (int r = 0; r < 4; ++r)
                    out[(base + quad * 4 + r) * (TSTEPS * 2) + (k - 1) * 2 + col] = eacc[r];
            }
            if (k > 0 && w == 3 && col < 2) {   // rel_{k-1}(T2)
                #pragma unroll
                for (int r = 0; r < 4; ++r)
                    out[(base + 32 + quad * 4 + r) * (TSTEPS * 2) + (k - 1) * 2 + col] = eacc[r];
            }
            __syncthreads();
        }
        // ============ ODD: gates(T1,T3;k) h-part ; finish+cell(T0,T2;k) ============
        {
            half8 a1[4], a3[4];
            #pragma unroll
            for (int kc = 0; kc < 4; ++kc) {
                a1[kc] = *(const half8*)&hS[16 + col][SWZ(16 + col, kc * 32 + quad * 8)];
                a3[kc] = *(const half8*)&hS[48 + col][SWZ(48 + col, kc * 32 + quad * 8)];
            }

            {   // finish gates(T0,T2;k): x part (xS = obs-x0 at k=0)
#if XK16
                const half4 x0 = *(const half4*)&xS[0][col][quad * 4];
                const half4 x2 = *(const half4*)&xS[2][col][quad * 4];
                #pragma unroll
                for (int nt = 0; nt < 4; ++nt) {
                    accT0[nt] = __builtin_amdgcn_mfma_f32_16x16x16f16(x0, Wf4[nt], accT0[nt], 0, 0, 0);
                    accT2[nt] = __builtin_amdgcn_mfma_f32_16x16x16f16(x2, Wf4[nt], accT2[nt], 0, 0, 0);
                }
#else
                const half8 x0 = *(const half8*)&xS[0][col][quad * 8];
                const half8 x2 = *(const half8*)&xS[2][col][quad * 8];
                #pragma unroll
                for (int nt = 0; nt < 4; ++nt) {
                    accT0[nt] = __builtin_amdgcn_mfma_f32_16x16x32_f16(x0, Wf[nt][4], accT0[nt], 0, 0, 0);
                    accT2[nt] = __builtin_amdgcn_mfma_f32_16x16x32_f16(x2, Wf[nt][4], accT2[nt], 0, 0, 0);
                }
#endif
            }

            #pragma unroll
            for (int nt = 0; nt < 4; ++nt) {
                f32x4 bv = {bias[nt], bias[nt], bias[nt], bias[nt]};
                accT1[nt] = bv;
                accT3[nt] = bv;
            }
            f32x4 eacc = {einit, einit, einit, einit};

            #pragma unroll
            for (int kc = 0; kc < 4; ++kc)
                #pragma unroll
                for (int nt = 0; nt < 4; ++nt) {
                    accT1[nt] = __builtin_amdgcn_mfma_f32_16x16x32_f16(a1[kc], Wf[nt][kc], accT1[nt], 0, 0, 0);
                    accT3[nt] = __builtin_amdgcn_mfma_f32_16x16x32_f16(a3[kc], Wf[nt][kc], accT3[nt], 0, 0, 0);
                }

            {   // cell(T0,T2;k) rows 0-1
                #pragma unroll
                for (int r = 0; r < 2; ++r) {
                    CELL_ROW(accT0, c[0][r], quad * 4 + r, r);
                    CELL_ROW(accT2, c[2][r], 32 + quad * 4 + r, r);
                }
            }

            if (w == 4) {        // x(T1): hi only
                #pragma unroll
                for (int kc = 0; kc < 4; ++kc)
                    eacc = __builtin_amdgcn_mfma_f32_16x16x32_f16(a1[kc], Ef[kc], eacc, 0, 0, 0);
            }
            if (w == 5) {        // x(T3): hi only
                #pragma unroll
                for (int kc = 0; kc < 4; ++kc)
                    eacc = __builtin_amdgcn_mfma_f32_16x16x32_f16(a3[kc], Ef[kc], eacc, 0, 0, 0);
            }
            if (w == 6) {        // rel(T1): hi + lo
                #pragma unroll
                for (int kc = 0; kc < 4; ++kc)
                    eacc = __builtin_amdgcn_mfma_f32_16x16x32_f16(a1[kc], Ef[kc], eacc, 0, 0, 0);
                #pragma unroll
                for (int kc = 0; kc < 4; ++kc) {
                    const half8 aL = *(const half8*)&lS[16 + col][SWZ(16 + col, kc * 32 + quad * 8)];
                    eacc = __builtin_amdgcn_mfma_f32_16x16x32_f16(aL, Ef[kc], eacc, 0, 0, 0);
                }
            }
            if (w == 7) {        // rel(T3): hi + lo
                #pragma unroll
                for (int kc = 0; kc < 4; ++kc)
                    eacc = __builtin_amdgcn_mfma_f32_16x16x32_f16(a3[kc], Ef[kc], eacc, 0, 0, 0);
                #pragma unroll
                for (int kc = 0; kc < 4; ++kc) {
                    const half8 aL = *(const half8*)&lS[48 + col][SWZ(48 + col, kc * 32 + quad * 8)];
                    eacc = __builtin_amdgcn_mfma_f32_16x16x32_f16(aL, Ef[kc], eacc, 0, 0, 0);
                }
            }

            {   // cell(T0,T2;k) rows 2-3
                #pragma unroll
                for (int r = 2; r < 4; ++r) {
                    CELL_ROW(accT0, c[0][r], quad * 4 + r, r);
                    CELL_ROW(accT2, c[2][r], 32 + quad * 4 + r, r);
                }
            }

            if (k > 0 && w == 4) {   // x_k(T1); k=0 keeps obs-x0
                #pragma unroll
                for (int r = 0; r < 4; ++r)
                    xS[1][quad * 4 + r][col] = (_Float16)ftanh_pre(eacc[r]);
            }
            if (k > 0 && w == 5) {   // x_k(T3)
                #pragma unroll
                for (int r = 0; r < 4; ++r)
                    xS[3][quad * 4 + r][col] = (_Float16)ftanh_pre(eacc[r]);
            }
            if (k > 0 && w == 6 && col < 2) {   // rel_{k-1}(T1)
                #pragma unroll
                for (int r = 0; r < 4; ++r)
                    out[(base + 16 + quad * 4 + r) * (TSTEPS * 2) + (k - 1) * 2 + col] = eacc[r];
            }
            if (k > 0 && w == 7 && col < 2) {   // rel_{k-1}(T3)
                #pragma unroll
                for (int r = 0; r < 4; ++r)
                    out[(base + 48 + quad * 4 + r) * (TSTEPS * 2) + (k - 1) * 2 + col] = eacc[r];
            }
            __syncthreads();
        }
    }

    // ============ epilogue: finish T1/T3 step 29; rel_29 all four tiles ============
    {
        {   // finish gates(T1,T3;29): x part
#if XK16
            const half4 x1 = *(const half4*)&xS[1][col][quad * 4];
            const half4 x3 = *(const half4*)&xS[3][col][quad * 4];
            #pragma unroll
            for (int nt = 0; nt < 4; ++nt) {
                accT1[nt] = __builtin_amdgcn_mfma_f32_16x16x16f16(x1, Wf4[nt], accT1[nt], 0, 0, 0);
                accT3[nt] = __builtin_amdgcn_mfma_f32_16x16x16f16(x3, Wf4[nt], accT3[nt], 0, 0, 0);
            }
#else
            const half8 x1 = *(const half8*)&xS[1][col][quad * 8];
            const half8 x3 = *(const half8*)&xS[3][col][quad * 8];
            #pragma unroll
            for (int nt = 0; nt < 4; ++nt) {
                accT1[nt] = __builtin_amdgcn_mfma_f32_16x16x32_f16(x1, Wf[nt][4], accT1[nt], 0, 0, 0);
                accT3[nt] = __builtin_amdgcn_mfma_f32_16x16x32_f16(x3, Wf[nt][4], accT3[nt], 0, 0, 0);
            }
#endif
        }
        if (w == 2) {   // rel_29(T0) from h_30(T0)
            f32x4 eacc = {einit, einit, einit, einit};
            #pragma unroll
            for (int kc = 0; kc < 4; ++kc) {
                const half8 aH = *(const half8*)&hS[col][SWZ(col, kc * 32 + quad * 8)];
                eacc = __builtin_amdgcn_mfma_f32_16x16x32_f16(aH, Ef[kc], eacc, 0, 0, 0);
            }
            #pragma unroll
            for (int kc = 0; kc < 4; ++kc) {
                const half8 aL = *(const half8*)&lS[col][SWZ(col, kc * 32 + quad * 8)];
                eacc = __builtin_amdgcn_mfma_f32_16x16x32_f16(aL, Ef[kc], eacc, 0, 0, 0);
            }
            if (col < 2) {
                #pragma unroll
                for (int r = 0; r < 4; ++r)
                    out[(base + quad * 4 + r) * (TSTEPS * 2) + (TSTEPS - 1) * 2 + col] = eacc[r];
            }
        }
        if (w == 3) {   // rel_29(T2) from h_30(T2)
            f32x4 eacc = {einit, einit, einit, einit};
            #pragma unroll
            for (int kc = 0; kc < 4; ++kc) {
                const half8 aH = *(const half8*)&hS[32 + col][SWZ(32 + col, kc * 32 + quad * 8)];
                eacc = __builtin_amdgcn_mfma_f32_16x16x32_f16(aH, Ef[kc], eacc, 0, 0, 0);
            }
            #pragma unroll
            for (int kc = 0; kc < 4; ++kc) {
                const half8 aL = *(const half8*)&lS[32 + col][SWZ(32 + col, kc * 32 + quad * 8)];
                eacc = __builtin_amdgcn_mfma_f32_16x16x32_f16(aL, Ef[kc], eacc, 0, 0, 0);
            }
            if (col < 2) {
                #pragma unroll
                for (int r = 0; r < 4; ++r)
                    out[(base + 32 + quad * 4 + r) * (TSTEPS * 2) + (TSTEPS - 1) * 2 + col] = eacc[r];
            }
        }
        #pragma unroll
        for (int r = 0; r < 4; ++r) {   // cell(T1,T3;29) -> h_30
            CELL_ROW(accT1, c[1][r], 16 + quad * 4 + r, r);
            CELL_ROW(accT3, c[3][r], 48 + quad * 4 + r, r);
        }
        __syncthreads();
        if (w == 6) {   // rel_29(T1) from h_30(T1)
            f32x4 eacc = {einit, einit, einit, einit};
            #pragma unroll
            for (int kc = 0; kc < 4; ++kc) {
                const half8 aH = *(const half8*)&hS[16 + col][SWZ(16 + col, kc * 32 + quad * 8)];
                eacc = __builtin_amdgcn_mfma_f32_16x16x32_f16(aH, Ef[kc], eacc, 0, 0, 0);
            }
            #pragma unroll
            for (int kc = 0; kc < 4; ++kc) {
                const half8 aL = *(const half8*)&lS[16 + col][SWZ(16 + col, kc * 32 + quad * 8)];
                eacc = __builtin_amdgcn_mfma_f32_16x16x32_f16(aL, Ef[kc], eacc, 0, 0, 0);
            }
            if (col < 2) {
                #pragma unroll
                for (int r = 0; r < 4; ++r)
                    out[(base + 16 + quad * 4 + r) * (TSTEPS * 2) + (TSTEPS - 1) * 2 + col] = eacc[r];
            }
        }
        if (w == 7) {   // rel_29(T3) from h_30(T3)
            f32x4 eacc = {einit, einit, einit, einit};
            #pragma unroll
            for (int kc = 0; kc < 4; ++kc) {
                const half8 aH = *(const half8*)&hS[48 + col][SWZ(48 + col, kc * 32 + quad * 8)];
                eacc = __builtin_amdgcn_mfma_f32_16x16x32_f16(aH, Ef[kc], eacc, 0, 0, 0);
            }
            #pragma unroll
            for (int kc = 0; kc < 4; ++kc) {
                const half8 aL = *(const half8*)&lS[48 + col][SWZ(48 + col, kc * 32 + quad * 8)];
                eacc = __builtin_amdgcn_mfma_f32_16x16x32_f16(aL, Ef[kc], eacc, 0, 0, 0);
            }
            if (col < 2) {
                #pragma unroll
                for (int r = 0; r < 4; ++r)
                    out[(base + 48 + quad * 4 + r) * (TSTEPS * 2) + (TSTEPS - 1) * 2 + col] = eacc[r];
            }
        }
    }
}

extern "C" void kernel_launch(void* const* d_in, const int* in_sizes, int n_in,
                              void* d_out, int out_size, void* d_ws, size_t ws_size,
                              hipStream_t stream) {
    const float* last_obs_rel = (const float*)d_in[1];
    const float* h0    = (const float*)d_in[2];
    const float* c0    = (const float*)d_in[3];
    const float* W_sp  = (const float*)d_in[4];
    const float* b_sp  = (const float*)d_in[5];
    const float* W_ih  = (const float*)d_in[6];
    const float* b_ih  = (const float*)d_in[7];
    const float* W_hh  = (const float*)d_in[8];
    const float* b_hh  = (const float*)d_in[9];
    const float* W_out = (const float*)d_in[10];
    const float* b_out = (const float*)d_in[11];
    float* out = (float*)d_out;

    const int batch = in_sizes[2] / 128;   // 65536
    lstm30_kernel<<<dim3(batch / 64), dim3(512), 0, stream>>>(
        last_obs_rel, h0, c0, W_sp, b_sp, W_ih, b_ih, W_hh, b_hh, W_out, b_out, out);
}